// Round 1
// 440.865 us; speedup vs baseline: 1.1392x; 1.1392x over previous
//
#include <hip/hip_runtime.h>
#include <limits.h>

#pragma clang fp contract(off)

#define NB 512
#define NC 151
#define KDIM 4096
#define KS 8
#define KCH (KDIM/KS)      // 512
#define GRB 16             // gemm rows per block
#define PST 152            // padded row stride (floats), 16B-aligned rows
#define NK 32              // commits per round (batch)
#define NL 16              // cached top-list depth per row
#define NMS_TH 0.3f

typedef unsigned long long ull;

// exact reference IoU arithmetic (fp contract off file-wide)
__device__ __forceinline__ bool overlap_ge(const float4& c, const float4& o) {
  float areaC = (c.z - c.x + 1.0f) * (c.w - c.y + 1.0f);
  float areaJ = (o.z - o.x + 1.0f) * (o.w - o.y + 1.0f);
  float iw = fminf(c.z, o.z) - fmaxf(c.x, o.x) + 1.0f;
  float ih = fminf(c.w, o.w) - fmaxf(c.y, o.y) + 1.0f;
  iw = fmaxf(iw, 0.0f); ih = fmaxf(ih, 0.0f);
  float inter = iw * ih;
  float uni = areaC + areaJ - inter;
  return inter / uni >= NMS_TH;
}

__device__ __forceinline__ bool mbit(const unsigned m[5], int c) {
  bool r = false;
#pragma unroll
  for (int k = 0; k < 5; ++k) r = (k == (c >> 5)) ? (((m[k] >> (c & 31)) & 1u) != 0) : r;
  return r;
}

// 64-bit shuffle-xor across the full wave64
__device__ __forceinline__ ull shflx_u64(ull v, int m) {
  int lo = (int)(unsigned)(v & 0xFFFFFFFFull);
  int hi = (int)(unsigned)(v >> 32);
  lo = __shfl_xor(lo, m, 64);
  hi = __shfl_xor(hi, m, 64);
  return ((ull)(unsigned)hi << 32) | (unsigned)lo;
}

// ---------------- kernel 1: fused GEMM split-K partials + boxes transpose ----------------
#define TPB_GEMM 256
#define NTR ((NB * NC + 191) / 192)   // 403
__global__ __launch_bounds__(192) void gemm_fused(
    const float* __restrict__ A, const float* __restrict__ W,
    const float* __restrict__ boxes, float* __restrict__ part, float* __restrict__ bt)
{
  if (blockIdx.x >= TPB_GEMM) {
    int i = (blockIdx.x - TPB_GEMM) * 192 + threadIdx.x;
    if (i < NB * NC) {
      int r = i / NC, c = i - r * NC;
      float4 v = *(const float4*)(boxes + (size_t)i * 4);      // coalesced read
      *(float4*)(bt + ((size_t)c * NB + r) * 4) = v;           // scattered write (once)
    }
    return;
  }
  __shared__ float sA[GRB * KCH];  // 32 KB
  int rb = blockIdx.x >> 3, ks = blockIdx.x & 7;
  const float* Ab = A + (size_t)rb * GRB * KDIM + (size_t)ks * KCH;
  for (int i = threadIdx.x; i < GRB * (KCH / 4); i += 192) {
    int r = i >> 7;            // KCH/4 = 128
    int k4 = i & 127;
    *(float4*)(sA + r * KCH + k4 * 4) = *(const float4*)(Ab + (size_t)r * KDIM + k4 * 4);
  }
  __syncthreads();
  int c = threadIdx.x;
  if (c < NC) {
    const float* wp = W + (size_t)ks * KCH * NC + c;
    float acc[GRB];
#pragma unroll
    for (int r = 0; r < GRB; ++r) acc[r] = 0.f;
    float w0 = wp[0], w1 = wp[NC], w2 = wp[2 * NC], w3 = wp[3 * NC];
    for (int k4 = 0; k4 < KCH / 4; ++k4) {
      int kn = (k4 + 1 < KCH / 4) ? (k4 + 1) : k4;     // clamp: re-read last (no OOB)
      const float* q = wp + (size_t)(4 * kn) * NC;
      float n0 = q[0], n1 = q[NC], n2 = q[2 * NC], n3 = q[3 * NC];
#pragma unroll
      for (int r = 0; r < GRB; ++r) {
        float4 a = *(const float4*)(sA + r * KCH + k4 * 4);  // broadcast read
        acc[r] = fmaf(a.x, w0, acc[r]);
        acc[r] = fmaf(a.y, w1, acc[r]);
        acc[r] = fmaf(a.z, w2, acc[r]);
        acc[r] = fmaf(a.w, w3, acc[r]);
      }
      w0 = n0; w1 = n1; w2 = n2; w3 = n3;
    }
    float* o = part + ((size_t)ks * NB + (size_t)rb * GRB) * PST + c;
#pragma unroll
    for (int r = 0; r < GRB; ++r) o[(size_t)r * PST] = acc[r];
  }
}

// ---------------- kernel 2: reduce + obj_dists + softmax probs + top-16 list ----------------
__global__ __launch_bounds__(64) void prep_kernel(
    const float* __restrict__ part, const float* __restrict__ bias,
    float* __restrict__ out, float* __restrict__ lp, float* __restrict__ tl)
{
  int j = blockIdx.x * 64 + threadIdx.x;
  if (j >= NB) return;
  float* pr = lp + (size_t)j * PST;
  float* orow = out + (size_t)j * NC;

  float m_ = -3.4e38f;
  for (int c4 = 0; c4 < PST / 4; ++c4) {
    float x0 = 0.f, x1 = 0.f, x2 = 0.f, x3 = 0.f;
#pragma unroll
    for (int ks = 0; ks < KS; ++ks) {
      const float4 v = *(const float4*)(part + ((size_t)ks * NB + j) * PST + c4 * 4);
      x0 += v.x; x1 += v.y; x2 += v.z; x3 += v.w;
    }
    int c = c4 * 4;
    x0 += bias[c];
    if (c + 1 < NC) x1 += bias[c + 1];
    if (c + 2 < NC) x2 += bias[c + 2];
    if (c + 3 < NC) x3 += bias[c + 3];
    float4 st; st.x = x0; st.y = (c + 1 < NC) ? x1 : -3.4e38f;
    st.z = (c + 2 < NC) ? x2 : -3.4e38f; st.w = (c + 3 < NC) ? x3 : -3.4e38f;
    *(float4*)(pr + c4 * 4) = st;
    orow[c] = x0;
    if (c + 1 < NC) orow[c + 1] = x1;
    if (c + 2 < NC) orow[c + 2] = x2;
    if (c + 3 < NC) orow[c + 3] = x3;
    m_ = fmaxf(m_, st.x); m_ = fmaxf(m_, st.y);
    m_ = fmaxf(m_, st.z); m_ = fmaxf(m_, st.w);
  }
  float s_ = 0.f;
  for (int c4 = 0; c4 < PST / 4; ++c4) {
    float4 v = *(const float4*)(pr + c4 * 4);
    s_ += expf(v.x - m_); s_ += expf(v.y - m_);
    s_ += expf(v.z - m_); s_ += expf(v.w - m_);    // pad: exp(-huge)=0
  }
  float lv[NL]; int lc[NL];
#pragma unroll
  for (int t = 0; t < NL; ++t) { lv[t] = -3.4e38f; lc[t] = 0; }
  for (int c4 = 0; c4 < PST / 4; ++c4) {
    float4 v = *(const float4*)(pr + c4 * 4);
    int c = c4 * 4;
    float p0 = (c == 0) ? 0.f : expf(v.x - m_) / s_;
    float p1 = expf(v.y - m_) / s_;
    float p2 = expf(v.z - m_) / s_;
    float p3 = expf(v.w - m_) / s_;
    float4 st; st.x = p0; st.y = p1; st.z = p2; st.w = p3;   // pad -> 0
    *(float4*)(pr + c4 * 4) = st;
#pragma unroll
    for (int u = 0; u < 4; ++u) {
      float pv = (u == 0) ? p0 : (u == 1) ? p1 : (u == 2) ? p2 : p3;
      int cc = c + u;
      if (pv > 0.f && pv > lv[NL - 1]) {
        lv[NL - 1] = pv; lc[NL - 1] = cc;
#pragma unroll
        for (int q = NL - 1; q > 0; --q) {
          if (lv[q] > lv[q - 1]) {
            float tv = lv[q]; lv[q] = lv[q - 1]; lv[q - 1] = tv;
            int tc = lc[q]; lc[q] = lc[q - 1]; lc[q - 1] = tc;
          }
        }
      }
    }
  }
  float* tr = tl + (size_t)j * (2 * NL);
#pragma unroll
  for (int t = 0; t < NL; ++t) { tr[t] = lv[t]; tr[NL + t] = __int_as_float(lc[t]); }
}

// fallback gemm (ws too small)
__global__ __launch_bounds__(192) void gemm_full(
    const float* __restrict__ A, const float* __restrict__ W,
    const float* __restrict__ bias, float* __restrict__ out)
{
  int c = threadIdx.x;
  int r0 = blockIdx.x * 4;
  if (c >= NC) return;
  const float* a = A + (size_t)r0 * KDIM;
  const float* wp = W + c;
  float a0 = 0.f, a1 = 0.f, a2 = 0.f, a3 = 0.f;
#pragma unroll 8
  for (int k = 0; k < KDIM; ++k) {
    float w = wp[(size_t)k * NC];
    a0 = fmaf(a[k],            w, a0);
    a1 = fmaf(a[k + KDIM],     w, a1);
    a2 = fmaf(a[k + 2 * KDIM], w, a2);
    a3 = fmaf(a[k + 3 * KDIM], w, a3);
  }
  float bb = bias[c];
  out[(size_t)(r0 + 0) * NC + c] = a0 + bb;
  out[(size_t)(r0 + 1) * NC + c] = a1 + bb;
  out[(size_t)(r0 + 2) * NC + c] = a2 + bb;
  out[(size_t)(r0 + 3) * NC + c] = a3 + bb;
}

// ---------------- Multi-commit greedy NMS decode (K=32, block-bitonic sort) ----------------
// cand key: (orderable(value) << 32) | (0xFFFFFFFF - flatidx) — u64 order ==
// (value desc, flatidx asc), exactly the reference argmax tie-break. Keys unique
// (flat embedded), so the bitonic network's output is deterministic.
// Per round: full 512-key bitonic sort across the block (39 shfl CE stages in
// parallel on all 8 waves + 6 LDS-exchange stages, ping-pong A/B, 1 barrier each)
// -> exact global top-32 sorted -> rare-conflict mask via class-first pair checks
// (496 pairs on 512 threads, LDS atomicOr only on class match) -> per-wave
// ballot + readlane prefix chain for p -> apply p commits (4 groups of 8,
// identical semantics to the verified K=16 version).
template <bool FAST>
__global__ __launch_bounds__(512) void decode_kernel(
    const float* __restrict__ lp, const float* __restrict__ tl,
    const float* __restrict__ boxes /* FAST: bt [NC][NB][4]; else raw */,
    float* __restrict__ commits)
{
  __shared__ ull bufA[NB];      // 4 KB
  __shared__ ull bufB[NB];      // 4 KB
  __shared__ int swin[NK];      // packed (row<<8)|cls
  __shared__ unsigned smask[NK];
  const int j = threadIdx.x;
  const int lane = j & 63;

  float lv[NL]; int lc[NL];
  float m_ = 0.f, s_ = 1.f;
  const float* xr = FAST ? (lp + (size_t)j * PST) : (lp + (size_t)j * NC);

  if (FAST) {
    const float4* tl4 = (const float4*)(tl + (size_t)j * (2 * NL));
#pragma unroll
    for (int q = 0; q < NL / 4; ++q) {
      float4 v = tl4[q];
      lv[4 * q] = v.x; lv[4 * q + 1] = v.y; lv[4 * q + 2] = v.z; lv[4 * q + 3] = v.w;
    }
#pragma unroll
    for (int q = 0; q < NL / 4; ++q) {
      float4 v = tl4[NL / 4 + q];
      lc[4 * q] = __float_as_int(v.x); lc[4 * q + 1] = __float_as_int(v.y);
      lc[4 * q + 2] = __float_as_int(v.z); lc[4 * q + 3] = __float_as_int(v.w);
    }
  } else {
#pragma unroll
    for (int t = 0; t < NL; ++t) { lv[t] = -3.4e38f; lc[t] = 0; }
    m_ = xr[0];
    for (int c = 1; c < NC; ++c) m_ = fmaxf(m_, xr[c]);
    s_ = 0.f;
    for (int c = 0; c < NC; ++c) s_ += expf(xr[c] - m_);
    for (int c = 1; c < NC; ++c) {
      float v = expf(xr[c] - m_) / s_;
      if (v > lv[NL - 1]) {
        lv[NL - 1] = v; lc[NL - 1] = c;
#pragma unroll
        for (int q = NL - 1; q > 0; --q) {
          if (lv[q] > lv[q - 1]) {
            float tv = lv[q]; lv[q] = lv[q - 1]; lv[q - 1] = tv;
            int tc = lc[q]; lc[q] = lc[q - 1]; lc[q - 1] = tc;
          }
        }
      }
    }
  }

  float rowmax; int argcls; bool zstuck = false;
  if (lv[0] > 0.f) { rowmax = lv[0]; argcls = lc[0]; }
  else { rowmax = 0.f; argcls = 0; zstuck = true; }

  unsigned mask[5] = {0, 0, 0, 0, 0};
  bool retired = false;
  int post_min = INT_MAX;
  int commitcls = 0;
  int committed = 0;

  while (committed < NB) {
    ull key;
    {
      unsigned u = __float_as_uint(rowmax);
      u ^= (u & 0x80000000u) ? 0xFFFFFFFFu : 0x80000000u;   // orderable encoding
      key = ((ull)u << 32) | (unsigned)(0xFFFFFFFFu - (unsigned)(j * NC + argcls));
    }

    // compare-exchange helpers: desc sort, direction from global thread id j.
    auto ce = [&](int kk, int dd) {
      ull o = shflx_u64(key, dd);
      bool km = (((j & dd) == 0) == ((j & kk) == 0));
      ull mx = key > o ? key : o, mn = key > o ? o : key;
      key = km ? mx : mn;
    };
    auto cem = [&](ull o, int kk, int dd) {
      bool km = (((j & dd) == 0) == ((j & kk) == 0));
      ull mx = key > o ? key : o, mn = key > o ? o : key;
      key = km ? mx : mn;
    };

    // ---- intra-wave bitonic stages k=2..64 (shfl only, all waves parallel) ----
#pragma unroll
    for (int kk = 2; kk <= 64; kk <<= 1) {
#pragma unroll
      for (int dd = kk >> 1; dd >= 1; dd >>= 1) ce(kk, dd);
    }

    __syncthreads();   // protect bufA/swin/smask from previous round's readers

    // ---- cross-wave merge stages (ping-pong A/B, one barrier each) ----
    bufA[j] = key; __syncthreads();
    cem(bufA[j ^ 64], 128, 64);
#pragma unroll
    for (int dd = 32; dd >= 1; dd >>= 1) ce(128, dd);

    bufB[j] = key; __syncthreads();
    cem(bufB[j ^ 128], 256, 128);
    bufA[j] = key; __syncthreads();
    cem(bufA[j ^ 64], 256, 64);
#pragma unroll
    for (int dd = 32; dd >= 1; dd >>= 1) ce(256, dd);

    bufB[j] = key; __syncthreads();
    cem(bufB[j ^ 256], 512, 256);
    bufA[j] = key; __syncthreads();
    cem(bufA[j ^ 128], 512, 128);
    bufB[j] = key; __syncthreads();
    cem(bufB[j ^ 64], 512, 64);
#pragma unroll
    for (int dd = 32; dd >= 1; dd >>= 1) ce(512, dd);

    bufA[j] = key;                 // bufA[t] = t-th largest key, exact
    if (j < NK) smask[j] = 0;
    __syncthreads();

    // ---- conflict detection: 496 pairs on 512 threads, class-compare first ----
    auto dkey = [&](ull kk, int& row, int& cls) {
      unsigned f = 0xFFFFFFFFu - (unsigned)kk;
      row = (int)(f / (unsigned)NC);
      cls = (int)(f - (unsigned)row * (unsigned)NC);
    };
    if (j < NK) {
      int r0, c0; dkey(bufA[j], r0, c0);
      swin[j] = (r0 << 8) | c0;
    }
    {
      int t = j >> 4, s0 = j & 15, s1 = s0 + 16;
      int rT, cT;   dkey(bufA[t],  rT,  cT);
      int rS0, cS0; dkey(bufA[s0], rS0, cS0);
      int rS1, cS1; dkey(bufA[s1], rS1, cS1);
      bool h0 = (s0 < t) && (cS0 == cT);   // rare (~1/150 per pair)
      bool h1 = (s1 < t) && (cS1 == cT);
      if (h0) {
        float4 bs, btx;
        if (FAST) {
          bs  = *(const float4*)(boxes + ((size_t)cT * NB + rS0) * 4);
          btx = *(const float4*)(boxes + ((size_t)cT * NB + rT) * 4);
        } else {
          bs  = *(const float4*)(boxes + ((size_t)rS0 * NC + cT) * 4);
          btx = *(const float4*)(boxes + ((size_t)rT * NC + cT) * 4);
        }
        if (overlap_ge(bs, btx)) atomicOr(&smask[t], 1u << s0);
      }
      if (h1) {
        float4 bs, btx;
        if (FAST) {
          bs  = *(const float4*)(boxes + ((size_t)cT * NB + rS1) * 4);
          btx = *(const float4*)(boxes + ((size_t)cT * NB + rT) * 4);
        } else {
          bs  = *(const float4*)(boxes + ((size_t)rS1 * NC + cT) * 4);
          btx = *(const float4*)(boxes + ((size_t)rT * NC + cT) * 4);
        }
        if (overlap_ge(bs, btx)) atomicOr(&smask[t], 1u << s1);
      }
    }
    __syncthreads();

    // ---- prefix-validity chain (per-wave, identical result everywhere) ----
    int p;
    {
      int kmax = NB - committed; if (kmax > NK) kmax = NK;
      unsigned hi_l = (unsigned)(bufA[lane & (NK - 1)] >> 32);
      unsigned sm_l = smask[lane & (NK - 1)];
      // lanes >= NK read duplicates; their ballot bits are forced false by lane<kmax.
      ull okb = __ballot((lane < kmax) && (hi_l > 0x80000000u)); // orderable(0.0)=0x80000000
      unsigned okm = (unsigned)okb;
      unsigned valid = 1u; p = 1;      // t=0 always commits (reference: argmax regardless of value)
#pragma unroll
      for (int t = 1; t < NK; ++t) {
        unsigned cm = (unsigned)__builtin_amdgcn_readlane((int)sm_l, t);
        bool ok = (p == t) && ((okm >> t) & 1u) && ((cm & valid) == 0u);
        if (ok) { valid |= (1u << t); p = t + 1; }
      }
    }

    // ---- all threads: apply the p commits in order, groups of 8 ----
#pragma unroll
    for (int g = 0; g < NK / 8; ++g) {
      if (g * 8 < p) {
        int rows_[8], cls_[8];
        float4 cb[8], ob[8];
#pragma unroll
        for (int u = 0; u < 8; ++u) {
          int t = g * 8 + u;
          int pkv = __builtin_amdgcn_readfirstlane(swin[t]);   // uniform scalar
          rows_[u] = pkv >> 8; cls_[u] = pkv & 255;
          if (t < p) {
            if (FAST) {
              const float* btc = boxes + (size_t)cls_[u] * NB * 4;
              cb[u] = *(const float4*)(btc + (size_t)rows_[u] * 4);  // s_load (uniform)
              ob[u] = *(const float4*)(btc + (size_t)j * 4);         // lane-dense
            } else {
              cb[u] = *(const float4*)(boxes + ((size_t)rows_[u] * NC + cls_[u]) * 4);
              ob[u] = *(const float4*)(boxes + ((size_t)j * NC + cls_[u]) * 4);
            }
          }
        }
#pragma unroll
        for (int u = 0; u < 8; ++u) {
          int t = g * 8 + u;
          if (t < p) {
            if (j == rows_[u]) {
              // commit: col update overwritten by row := -1 (reference order)
              retired = true; commitcls = cls_[u]; post_min = INT_MAX;
            } else if (overlap_ge(cb[u], ob[u])) {
              if (retired) {
                post_min = (cls_[u] < post_min) ? cls_[u] : post_min;  // resurrect -1 -> 0.0
              } else {
                int c = cls_[u];
#pragma unroll
                for (int k5b = 0; k5b < 5; ++k5b) if (k5b == (c >> 5)) mask[k5b] |= (1u << (c & 31));
              }
            }
          }
        }
      }
    }

    // ---- event-driven candidate recompute ----
    if (retired) {
      rowmax = (post_min != INT_MAX) ? 0.0f : -1.0f;
      argcls = (post_min != INT_MAX) ? post_min : 0;
    } else if (!zstuck && mbit(mask, argcls)) {
      // my class was just suppressed: scan cached top-16
      bool found = false;
#pragma unroll
      for (int t = 0; t < NL; ++t) {
        if (!found && lv[t] > 0.f && !mbit(mask, lc[t])) {
          rowmax = lv[t]; argcls = lc[t]; found = true;
        }
      }
      if (!found) {
        // cheap max-only rescan over stored probs (FAST) / expf recompute (fallback)
        float bm = -3.4e38f; int ba = 0;
        if (FAST) {
          for (int c4 = 0; c4 < PST / 4; ++c4) {
            float4 v4 = *(const float4*)(xr + c4 * 4);   // probs; class0=0, pad=0
            int c = c4 * 4;
            float vals[4] = {v4.x, v4.y, v4.z, v4.w};
#pragma unroll
            for (int u = 0; u < 4; ++u) {
              int cc = c + u;
              float v = mbit(mask, cc) ? 0.f : vals[u];
              if (v > bm) { bm = v; ba = cc; }   // cc=0 (v=0) hits first; pads never exceed
            }
          }
        } else {
          for (int c = 0; c < NC; ++c) {
            float v;
            if (c == 0) v = 0.f;
            else v = mbit(mask, c) ? 0.f : (expf(xr[c] - m_) / s_);
            if (v > bm) { bm = v; ba = c; }
          }
        }
        rowmax = bm; argcls = ba;
        if (!(bm > 0.f)) zstuck = true;   // all-zero row: candidate stable forever
      }
    }
    // zstuck: keep (rowmax=0, argcls) — values never increase for this row

    committed += p;
  }

  commits[j] = (float)commitcls;
}

extern "C" void kernel_launch(void* const* d_in, const int* in_sizes, int n_in,
                              void* d_out, int out_size, void* d_ws, size_t ws_size,
                              hipStream_t stream) {
  const float* A     = (const float*)d_in[0];   // obj_fmap [512,4096]
  const float* boxes = (const float*)d_in[1];   // boxes_per_cls [512,151,4]
  const float* W     = (const float*)d_in[2];   // [4096,151]
  const float* bias  = (const float*)d_in[3];   // [151]
  float* out = (float*)d_out;                   // [512*151] obj_dists ++ [512] commits

  const size_t np = (size_t)KS * NB * PST;      // part
  const size_t nl = (size_t)NB * PST;           // lp
  const size_t nt = (size_t)NB * (2 * NL);      // tl
  const size_t nb = (size_t)NC * NB * 4;        // bt
  const size_t need = (np + nl + nt + nb) * 4;

  if (ws_size >= need) {
    float* part = (float*)d_ws;
    float* lp   = part + np;
    float* tl   = lp + nl;
    float* bt   = tl + nt;
    gemm_fused<<<TPB_GEMM + NTR, 192, 0, stream>>>(A, W, boxes, part, bt);
    prep_kernel<<<NB / 64, 64, 0, stream>>>(part, bias, out, lp, tl);
    decode_kernel<true><<<1, NB, 0, stream>>>(lp, tl, bt, out + NB * NC);
  } else {
    gemm_full<<<NB / 4, 192, 0, stream>>>(A, W, bias, out);
    decode_kernel<false><<<1, NB, 0, stream>>>(out, nullptr, boxes, out + NB * NC);
  }
}

// Round 2
// 411.853 us; speedup vs baseline: 1.2194x; 1.0704x over previous
//
#include <hip/hip_runtime.h>
#include <limits.h>

#pragma clang fp contract(off)

#define NB 512
#define NC 151
#define KDIM 4096
#define KS 8
#define KCH (KDIM/KS)      // 512
#define GRB 16             // gemm rows per block
#define PST 152            // padded row stride (floats), 16B-aligned rows
#define NK 64              // commits per round (batch)
#define NL 16              // cached top-list depth per row
#define NMS_TH 0.3f

typedef unsigned long long ull;

// exact reference IoU arithmetic (fp contract off file-wide)
__device__ __forceinline__ bool overlap_ge(const float4& c, const float4& o) {
  float areaC = (c.z - c.x + 1.0f) * (c.w - c.y + 1.0f);
  float areaJ = (o.z - o.x + 1.0f) * (o.w - o.y + 1.0f);
  float iw = fminf(c.z, o.z) - fmaxf(c.x, o.x) + 1.0f;
  float ih = fminf(c.w, o.w) - fmaxf(c.y, o.y) + 1.0f;
  iw = fmaxf(iw, 0.0f); ih = fmaxf(ih, 0.0f);
  float inter = iw * ih;
  float uni = areaC + areaJ - inter;
  return inter / uni >= NMS_TH;
}

__device__ __forceinline__ bool mbit(const unsigned m[5], int c) {
  bool r = false;
#pragma unroll
  for (int k = 0; k < 5; ++k) r = (k == (c >> 5)) ? (((m[k] >> (c & 31)) & 1u) != 0) : r;
  return r;
}

// 64-bit shuffle-xor across the full wave64
__device__ __forceinline__ ull shflx_u64(ull v, int m) {
  int lo = (int)(unsigned)(v & 0xFFFFFFFFull);
  int hi = (int)(unsigned)(v >> 32);
  lo = __shfl_xor(lo, m, 64);
  hi = __shfl_xor(hi, m, 64);
  return ((ull)(unsigned)hi << 32) | (unsigned)lo;
}

__device__ __forceinline__ ull readlane_u64(ull v, int t) {
  int lo = __builtin_amdgcn_readlane((int)(unsigned)(v & 0xFFFFFFFFull), t);
  int hi = __builtin_amdgcn_readlane((int)(unsigned)(v >> 32), t);
  return ((ull)(unsigned)hi << 32) | (unsigned)lo;
}

// ---------------- kernel 1: fused GEMM split-K partials + boxes transpose ----------------
#define TPB_GEMM 256
#define NTR ((NB * NC + 191) / 192)   // 403
__global__ __launch_bounds__(192) void gemm_fused(
    const float* __restrict__ A, const float* __restrict__ W,
    const float* __restrict__ boxes, float* __restrict__ part, float* __restrict__ bt)
{
  if (blockIdx.x >= TPB_GEMM) {
    int i = (blockIdx.x - TPB_GEMM) * 192 + threadIdx.x;
    if (i < NB * NC) {
      int r = i / NC, c = i - r * NC;
      float4 v = *(const float4*)(boxes + (size_t)i * 4);      // coalesced read
      *(float4*)(bt + ((size_t)c * NB + r) * 4) = v;           // scattered write (once)
    }
    return;
  }
  __shared__ float sA[GRB * KCH];  // 32 KB
  int rb = blockIdx.x >> 3, ks = blockIdx.x & 7;
  const float* Ab = A + (size_t)rb * GRB * KDIM + (size_t)ks * KCH;
  for (int i = threadIdx.x; i < GRB * (KCH / 4); i += 192) {
    int r = i >> 7;            // KCH/4 = 128
    int k4 = i & 127;
    *(float4*)(sA + r * KCH + k4 * 4) = *(const float4*)(Ab + (size_t)r * KDIM + k4 * 4);
  }
  __syncthreads();
  int c = threadIdx.x;
  if (c < NC) {
    const float* wp = W + (size_t)ks * KCH * NC + c;
    float acc[GRB];
#pragma unroll
    for (int r = 0; r < GRB; ++r) acc[r] = 0.f;
    float w0 = wp[0], w1 = wp[NC], w2 = wp[2 * NC], w3 = wp[3 * NC];
    for (int k4 = 0; k4 < KCH / 4; ++k4) {
      int kn = (k4 + 1 < KCH / 4) ? (k4 + 1) : k4;     // clamp: re-read last (no OOB)
      const float* q = wp + (size_t)(4 * kn) * NC;
      float n0 = q[0], n1 = q[NC], n2 = q[2 * NC], n3 = q[3 * NC];
#pragma unroll
      for (int r = 0; r < GRB; ++r) {
        float4 a = *(const float4*)(sA + r * KCH + k4 * 4);  // broadcast read
        acc[r] = fmaf(a.x, w0, acc[r]);
        acc[r] = fmaf(a.y, w1, acc[r]);
        acc[r] = fmaf(a.z, w2, acc[r]);
        acc[r] = fmaf(a.w, w3, acc[r]);
      }
      w0 = n0; w1 = n1; w2 = n2; w3 = n3;
    }
    float* o = part + ((size_t)ks * NB + (size_t)rb * GRB) * PST + c;
#pragma unroll
    for (int r = 0; r < GRB; ++r) o[(size_t)r * PST] = acc[r];
  }
}

// ---------------- kernel 2: reduce + obj_dists + softmax probs + top-16 list ----------------
__global__ __launch_bounds__(64) void prep_kernel(
    const float* __restrict__ part, const float* __restrict__ bias,
    float* __restrict__ out, float* __restrict__ lp, float* __restrict__ tl)
{
  int j = blockIdx.x * 64 + threadIdx.x;
  if (j >= NB) return;
  float* pr = lp + (size_t)j * PST;
  float* orow = out + (size_t)j * NC;

  float m_ = -3.4e38f;
  for (int c4 = 0; c4 < PST / 4; ++c4) {
    float x0 = 0.f, x1 = 0.f, x2 = 0.f, x3 = 0.f;
#pragma unroll
    for (int ks = 0; ks < KS; ++ks) {
      const float4 v = *(const float4*)(part + ((size_t)ks * NB + j) * PST + c4 * 4);
      x0 += v.x; x1 += v.y; x2 += v.z; x3 += v.w;
    }
    int c = c4 * 4;
    x0 += bias[c];
    if (c + 1 < NC) x1 += bias[c + 1];
    if (c + 2 < NC) x2 += bias[c + 2];
    if (c + 3 < NC) x3 += bias[c + 3];
    float4 st; st.x = x0; st.y = (c + 1 < NC) ? x1 : -3.4e38f;
    st.z = (c + 2 < NC) ? x2 : -3.4e38f; st.w = (c + 3 < NC) ? x3 : -3.4e38f;
    *(float4*)(pr + c4 * 4) = st;
    orow[c] = x0;
    if (c + 1 < NC) orow[c + 1] = x1;
    if (c + 2 < NC) orow[c + 2] = x2;
    if (c + 3 < NC) orow[c + 3] = x3;
    m_ = fmaxf(m_, st.x); m_ = fmaxf(m_, st.y);
    m_ = fmaxf(m_, st.z); m_ = fmaxf(m_, st.w);
  }
  float s_ = 0.f;
  for (int c4 = 0; c4 < PST / 4; ++c4) {
    float4 v = *(const float4*)(pr + c4 * 4);
    s_ += expf(v.x - m_); s_ += expf(v.y - m_);
    s_ += expf(v.z - m_); s_ += expf(v.w - m_);    // pad: exp(-huge)=0
  }
  float lv[NL]; int lc[NL];
#pragma unroll
  for (int t = 0; t < NL; ++t) { lv[t] = -3.4e38f; lc[t] = 0; }
  for (int c4 = 0; c4 < PST / 4; ++c4) {
    float4 v = *(const float4*)(pr + c4 * 4);
    int c = c4 * 4;
    float p0 = (c == 0) ? 0.f : expf(v.x - m_) / s_;
    float p1 = expf(v.y - m_) / s_;
    float p2 = expf(v.z - m_) / s_;
    float p3 = expf(v.w - m_) / s_;
    float4 st; st.x = p0; st.y = p1; st.z = p2; st.w = p3;   // pad -> 0
    *(float4*)(pr + c4 * 4) = st;
#pragma unroll
    for (int u = 0; u < 4; ++u) {
      float pv = (u == 0) ? p0 : (u == 1) ? p1 : (u == 2) ? p2 : p3;
      int cc = c + u;
      if (pv > 0.f && pv > lv[NL - 1]) {
        lv[NL - 1] = pv; lc[NL - 1] = cc;
#pragma unroll
        for (int q = NL - 1; q > 0; --q) {
          if (lv[q] > lv[q - 1]) {
            float tv = lv[q]; lv[q] = lv[q - 1]; lv[q - 1] = tv;
            int tc = lc[q]; lc[q] = lc[q - 1]; lc[q - 1] = tc;
          }
        }
      }
    }
  }
  float* tr = tl + (size_t)j * (2 * NL);
#pragma unroll
  for (int t = 0; t < NL; ++t) { tr[t] = lv[t]; tr[NL + t] = __int_as_float(lc[t]); }
}

// fallback gemm (ws too small)
__global__ __launch_bounds__(192) void gemm_full(
    const float* __restrict__ A, const float* __restrict__ W,
    const float* __restrict__ bias, float* __restrict__ out)
{
  int c = threadIdx.x;
  int r0 = blockIdx.x * 4;
  if (c >= NC) return;
  const float* a = A + (size_t)r0 * KDIM;
  const float* wp = W + c;
  float a0 = 0.f, a1 = 0.f, a2 = 0.f, a3 = 0.f;
#pragma unroll 8
  for (int k = 0; k < KDIM; ++k) {
    float w = wp[(size_t)k * NC];
    a0 = fmaf(a[k],            w, a0);
    a1 = fmaf(a[k + KDIM],     w, a1);
    a2 = fmaf(a[k + 2 * KDIM], w, a2);
    a3 = fmaf(a[k + 3 * KDIM], w, a3);
  }
  float bb = bias[c];
  out[(size_t)(r0 + 0) * NC + c] = a0 + bb;
  out[(size_t)(r0 + 1) * NC + c] = a1 + bb;
  out[(size_t)(r0 + 2) * NC + c] = a2 + bb;
  out[(size_t)(r0 + 3) * NC + c] = a3 + bb;
}

// ---------------- Multi-commit greedy NMS decode (K=64, merge-tree top-64) ----------------
// cand key: (orderable(value) << 32) | (0xFFFFFFFF - flatidx) — u64 order ==
// (value desc, flatidx asc), exactly the reference argmax tie-break. Keys unique.
// Per round:
//   per-wave bitonic sort-64 desc (21 shfl steps, all 8 waves parallel)
//   -> 3-level LDS merge tree keeping exact top-64 (Batcher max-trick:
//      {max(A[l],B[63-l])} == top-64 of A∪B, bitonic -> 6-step desc merge),
//      5 barriers/round total
//   -> exact global top-64 sorted on wave0 -> publish keys/swin/smask
//   -> conflict mask: 64x64 s<t pairs on 512 threads (8 each, b128 swin reads,
//      class-compare first, rare IoU + atomicOr)
//   -> per-wave uniform prefix-validity chain (ballot + readlane, exact
//      prefix-stop semantics preserved) -> apply p commits (rolled groups of 8).
// Probe: wave7 issues 2 fully-bank-conflicted LDS reads per round while idle ->
// SQ_LDS_BANK_CONFLICT ≈ 62 * rounds (empirical round counter, zero wall cost).
template <bool FAST>
__global__ __launch_bounds__(512) void decode_kernel(
    const float* __restrict__ lp, const float* __restrict__ tl,
    const float* __restrict__ boxes /* FAST: bt [NC][NB][4]; else raw */,
    float* __restrict__ commits)
{
  __shared__ ull bufA[NB];                 // 4 KB
  __shared__ ull bufB[NB];                 // 4 KB
  __shared__ __align__(16) int swin[NK];   // packed (row<<8)|cls
  __shared__ ull smask[NK];
  const int j = threadIdx.x;
  const int lane = j & 63;
  const int w = j >> 6;

  float lv[NL]; int lc[NL];
  float m_ = 0.f, s_ = 1.f;
  const float* xr = FAST ? (lp + (size_t)j * PST) : (lp + (size_t)j * NC);

  if (FAST) {
    const float4* tl4 = (const float4*)(tl + (size_t)j * (2 * NL));
#pragma unroll
    for (int q = 0; q < NL / 4; ++q) {
      float4 v = tl4[q];
      lv[4 * q] = v.x; lv[4 * q + 1] = v.y; lv[4 * q + 2] = v.z; lv[4 * q + 3] = v.w;
    }
#pragma unroll
    for (int q = 0; q < NL / 4; ++q) {
      float4 v = tl4[NL / 4 + q];
      lc[4 * q] = __float_as_int(v.x); lc[4 * q + 1] = __float_as_int(v.y);
      lc[4 * q + 2] = __float_as_int(v.z); lc[4 * q + 3] = __float_as_int(v.w);
    }
  } else {
#pragma unroll
    for (int t = 0; t < NL; ++t) { lv[t] = -3.4e38f; lc[t] = 0; }
    m_ = xr[0];
    for (int c = 1; c < NC; ++c) m_ = fmaxf(m_, xr[c]);
    s_ = 0.f;
    for (int c = 0; c < NC; ++c) s_ += expf(xr[c] - m_);
    for (int c = 1; c < NC; ++c) {
      float v = expf(xr[c] - m_) / s_;
      if (v > lv[NL - 1]) {
        lv[NL - 1] = v; lc[NL - 1] = c;
#pragma unroll
        for (int q = NL - 1; q > 0; --q) {
          if (lv[q] > lv[q - 1]) {
            float tv = lv[q]; lv[q] = lv[q - 1]; lv[q - 1] = tv;
            int tc = lc[q]; lc[q] = lc[q - 1]; lc[q - 1] = tc;
          }
        }
      }
    }
  }

  float rowmax; int argcls; bool zstuck = false;
  if (lv[0] > 0.f) { rowmax = lv[0]; argcls = lc[0]; }
  else { rowmax = 0.f; argcls = 0; zstuck = true; }

  unsigned mask[5] = {0, 0, 0, 0, 0};
  bool retired = false;
  int post_min = INT_MAX;
  int commitcls = 0;
  int committed = 0;

  while (committed < NB) {
    ull key;
    {
      unsigned u = __float_as_uint(rowmax);
      u ^= (u & 0x80000000u) ? 0xFFFFFFFFu : 0x80000000u;   // orderable encoding
      key = ((ull)u << 32) | (unsigned)(0xFFFFFFFFu - (unsigned)(j * NC + argcls));
    }

    // 6-step descending bitonic merge of a bitonic 64-seq (in-wave)
    auto mergeDesc = [&]() {
#pragma unroll
      for (int dd = 32; dd >= 1; dd >>= 1) {
        ull o = shflx_u64(key, dd);
        bool km = ((lane & dd) == 0);
        ull mx = key > o ? key : o, mn = key > o ? o : key;
        key = km ? mx : mn;
      }
    };

    // ---- per-wave bitonic sort-64 desc (21 steps) ----
#pragma unroll
    for (int kk = 2; kk <= 32; kk <<= 1) {
#pragma unroll
      for (int dd = kk >> 1; dd >= 1; dd >>= 1) {
        ull o = shflx_u64(key, dd);
        bool km = (((lane & dd) == 0) == ((lane & kk) == 0));
        ull mx = key > o ? key : o, mn = key > o ? o : key;
        key = km ? mx : mn;
      }
    }
    mergeDesc();

    bufA[j] = key;
    __syncthreads();   // B1

    // ---- level 1: waves 0-3 merge sorted-64 pairs, keep top-64 ----
    if (w < 4) {
      ull a = bufA[w * 128 + lane];
      ull b = bufA[w * 128 + 64 + (63 - lane)];
      key = a > b ? a : b;           // exact top-64 of the pair (bitonic)
      mergeDesc();
      bufB[w * 64 + lane] = key;
    } else if (w == 7) {
      // rounds probe: 2 fully-conflicted LDS reads (32 lanes -> 1 bank each)
      volatile int* pb = (volatile int*)bufA;
      int t0 = pb[(lane & 31) * 32];
      int t1 = pb[(lane & 31) * 32 + 1];
      asm volatile("" :: "v"(t0), "v"(t1));
    }
    __syncthreads();   // B2

    // ---- level 2: waves 0-1 ----
    if (w < 2) {
      ull a = bufB[w * 128 + lane];
      ull b = bufB[w * 128 + 64 + (63 - lane)];
      key = a > b ? a : b;
      mergeDesc();
      bufA[w * 64 + lane] = key;
    }
    __syncthreads();   // B3

    // ---- level 3: wave 0 -> exact global top-64 sorted desc; publish ----
    if (w == 0) {
      ull a = bufA[lane];
      ull b = bufA[64 + (63 - lane)];
      key = a > b ? a : b;
      mergeDesc();
      bufB[lane] = key;
      unsigned f = 0xFFFFFFFFu - (unsigned)key;
      int row = (int)(f / (unsigned)NC);
      int cls = (int)(f - (unsigned)row * (unsigned)NC);
      swin[lane] = (row << 8) | cls;
      smask[lane] = 0ull;
    }
    __syncthreads();   // B4

    // ---- conflict detection: all 64x64 (s<t) pairs, 8 per thread ----
    {
      int t = j >> 3, sb = (j & 7) * 8;
      int pT = swin[t];
      int cT = pT & 255, rT = pT >> 8;
      int4 sA4 = *(const int4*)&swin[sb];
      int4 sB4 = *(const int4*)&swin[sb + 4];
      int ss[8] = {sA4.x, sA4.y, sA4.z, sA4.w, sB4.x, sB4.y, sB4.z, sB4.w};
      ull myc = 0ull;
#pragma unroll
      for (int u = 0; u < 8; ++u) {
        int s = sb + u;
        if (s < t && (ss[u] & 255) == cT) {      // rare (~1/150 per pair)
          int rS = ss[u] >> 8;
          float4 bs, btx;
          if (FAST) {
            bs  = *(const float4*)(boxes + ((size_t)cT * NB + rS) * 4);
            btx = *(const float4*)(boxes + ((size_t)cT * NB + rT) * 4);
          } else {
            bs  = *(const float4*)(boxes + ((size_t)rS * NC + cT) * 4);
            btx = *(const float4*)(boxes + ((size_t)rT * NC + cT) * 4);
          }
          if (overlap_ge(bs, btx)) myc |= (1ull << s);
        }
      }
      if (myc) atomicOr(&smask[t], myc);
    }
    __syncthreads();   // B5

    // ---- prefix-validity chain (per-wave, identical result everywhere) ----
    int p;
    {
      int kmax = NB - committed; if (kmax > NK) kmax = NK;
      ull kv = bufB[lane];       // candidate 'lane' key
      ull sm = smask[lane];
      ull okm = __ballot((lane < kmax) &&
                         ((unsigned)(kv >> 32) > 0x80000000u));  // orderable(0.0)=0x80000000
      ull valid = 1ull; p = 1;   // t=0 always commits (reference: argmax regardless of value)
#pragma unroll
      for (int t = 1; t < NK; ++t) {
        ull cm = readlane_u64(sm, t);
        bool ok = (p == t) && ((okm >> t) & 1ull) && ((cm & valid) == 0ull);
        if (ok) { valid |= (1ull << t); p = t + 1; }
      }
    }

    // ---- all threads: apply the p commits in order, rolled groups of 8 ----
#pragma unroll 1
    for (int g = 0; g * 8 < p; ++g) {
      int rows_[8], cls_[8];
      float4 cb[8], ob[8];
#pragma unroll
      for (int u = 0; u < 8; ++u) {
        int t = g * 8 + u;
        int pkv = __builtin_amdgcn_readfirstlane(swin[t]);   // uniform scalar
        rows_[u] = pkv >> 8; cls_[u] = pkv & 255;
        if (t < p) {
          if (FAST) {
            const float* btc = boxes + (size_t)cls_[u] * NB * 4;
            cb[u] = *(const float4*)(btc + (size_t)rows_[u] * 4);  // s_load (uniform)
            ob[u] = *(const float4*)(btc + (size_t)j * 4);         // lane-dense
          } else {
            cb[u] = *(const float4*)(boxes + ((size_t)rows_[u] * NC + cls_[u]) * 4);
            ob[u] = *(const float4*)(boxes + ((size_t)j * NC + cls_[u]) * 4);
          }
        }
      }
#pragma unroll
      for (int u = 0; u < 8; ++u) {
        int t = g * 8 + u;
        if (t < p) {
          if (j == rows_[u]) {
            // commit: col update overwritten by row := -1 (reference order)
            retired = true; commitcls = cls_[u]; post_min = INT_MAX;
          } else if (overlap_ge(cb[u], ob[u])) {
            if (retired) {
              post_min = (cls_[u] < post_min) ? cls_[u] : post_min;  // resurrect -1 -> 0.0
            } else {
              int c = cls_[u];
#pragma unroll
              for (int k5b = 0; k5b < 5; ++k5b) if (k5b == (c >> 5)) mask[k5b] |= (1u << (c & 31));
            }
          }
        }
      }
    }

    // ---- event-driven candidate recompute ----
    if (retired) {
      rowmax = (post_min != INT_MAX) ? 0.0f : -1.0f;
      argcls = (post_min != INT_MAX) ? post_min : 0;
    } else if (!zstuck && mbit(mask, argcls)) {
      // my class was just suppressed: scan cached top-16
      bool found = false;
#pragma unroll
      for (int t = 0; t < NL; ++t) {
        if (!found && lv[t] > 0.f && !mbit(mask, lc[t])) {
          rowmax = lv[t]; argcls = lc[t]; found = true;
        }
      }
      if (!found) {
        // cheap max-only rescan over stored probs (FAST) / expf recompute (fallback)
        float bm = -3.4e38f; int ba = 0;
        if (FAST) {
          for (int c4 = 0; c4 < PST / 4; ++c4) {
            float4 v4 = *(const float4*)(xr + c4 * 4);   // probs; class0=0, pad=0
            int c = c4 * 4;
            float vals[4] = {v4.x, v4.y, v4.z, v4.w};
#pragma unroll
            for (int u = 0; u < 4; ++u) {
              int cc = c + u;
              float v = mbit(mask, cc) ? 0.f : vals[u];
              if (v > bm) { bm = v; ba = cc; }   // cc=0 (v=0) hits first; pads never exceed
            }
          }
        } else {
          for (int c = 0; c < NC; ++c) {
            float v;
            if (c == 0) v = 0.f;
            else v = mbit(mask, c) ? 0.f : (expf(xr[c] - m_) / s_);
            if (v > bm) { bm = v; ba = c; }
          }
        }
        rowmax = bm; argcls = ba;
        if (!(bm > 0.f)) zstuck = true;   // all-zero row: candidate stable forever
      }
    }
    // zstuck: keep (rowmax=0, argcls) — values never increase for this row

    committed += p;
  }

  commits[j] = (float)commitcls;
}

extern "C" void kernel_launch(void* const* d_in, const int* in_sizes, int n_in,
                              void* d_out, int out_size, void* d_ws, size_t ws_size,
                              hipStream_t stream) {
  const float* A     = (const float*)d_in[0];   // obj_fmap [512,4096]
  const float* boxes = (const float*)d_in[1];   // boxes_per_cls [512,151,4]
  const float* W     = (const float*)d_in[2];   // [4096,151]
  const float* bias  = (const float*)d_in[3];   // [151]
  float* out = (float*)d_out;                   // [512*151] obj_dists ++ [512] commits

  const size_t np = (size_t)KS * NB * PST;      // part
  const size_t nl = (size_t)NB * PST;           // lp
  const size_t nt = (size_t)NB * (2 * NL);      // tl
  const size_t nb = (size_t)NC * NB * 4;        // bt
  const size_t need = (np + nl + nt + nb) * 4;

  if (ws_size >= need) {
    float* part = (float*)d_ws;
    float* lp   = part + np;
    float* tl   = lp + nl;
    float* bt   = tl + nt;
    gemm_fused<<<TPB_GEMM + NTR, 192, 0, stream>>>(A, W, boxes, part, bt);
    prep_kernel<<<NB / 64, 64, 0, stream>>>(part, bias, out, lp, tl);
    decode_kernel<true><<<1, NB, 0, stream>>>(lp, tl, bt, out + NB * NC);
  } else {
    gemm_full<<<NB / 4, 192, 0, stream>>>(A, W, bias, out);
    decode_kernel<false><<<1, NB, 0, stream>>>(out, nullptr, boxes, out + NB * NC);
  }
}